// Round 2
// baseline (295.800 us; speedup 1.0000x reference)
//
#include <hip/hip_runtime.h>

// MultiHeadSelfAttention: N=4 S=2048 E=1024 H=16 D=64
// Pipeline: proj(QKV, bf16 MFMA) -> transpose V -> conv Wo -> flash attn -> out GEMM
// Workspace layout (needs 4*16MiB + 2MiB = 69,206,016 B):
//   Qp [NH][S][64] bf16 @ 0
//   Kp [NH][S][64] bf16 @ 16 MiB
//   Vt [NH][64][S] bf16 @ 32 MiB
//   Vp [NH][S][64] bf16 @ 48 MiB  (reused as AO [N][S][E] bf16 after transpose)
//   Wob [1024][1024] bf16 @ 64 MiB

using f32x4  = __attribute__((ext_vector_type(4))) float;
using bf16x8 = __attribute__((ext_vector_type(8))) __bf16;
using u32x4  = __attribute__((ext_vector_type(4))) unsigned int;
using u16x8  = __attribute__((ext_vector_type(8))) unsigned short;
typedef unsigned short u16;
typedef unsigned int   u32;
typedef unsigned long long u64;

#define SEQ 2048
#define EMB 1024
#define NHEADS 16
#define HDIM 64
#define NBATCH 4
#define NH 64  // NBATCH*NHEADS

__device__ __forceinline__ u16 f2bf(float f) {
  u32 u = __builtin_bit_cast(u32, f);
  return (u16)((u + 0x7fffu + ((u >> 16) & 1u)) >> 16);
}

__device__ __forceinline__ f32x4 mfma16(bf16x8 a, bf16x8 b, f32x4 c) {
  return __builtin_amdgcn_mfma_f32_16x16x32_bf16(a, b, c, 0, 0, 0);
}

__device__ __forceinline__ bf16x8 cvt8(f32x4 a, f32x4 b) {
  u16x8 r;
  r[0] = f2bf(a[0]); r[1] = f2bf(a[1]); r[2] = f2bf(a[2]); r[3] = f2bf(a[3]);
  r[4] = f2bf(b[0]); r[5] = f2bf(b[1]); r[6] = f2bf(b[2]); r[7] = f2bf(b[3]);
  return __builtin_bit_cast(bf16x8, r);
}

// ---------------------------------------------------------------------------
// Projection: per-head y = x @ W^T, X rows g=(n*S+s)*H+h are contiguous [64].
// Out = [NH][S][64] bf16. Wq is pre-scaled by 1/32 (softmax scale, exact pow2).
// Block: 256 thr, 64 rows; wave w handles rows g0+w*16..+15; 8 MFMAs/wave.
__global__ __launch_bounds__(256) void proj_kernel(
    const float* __restrict__ Xq, const float* __restrict__ Xk, const float* __restrict__ Xv,
    const float* __restrict__ Wq, const float* __restrict__ Wk, const float* __restrict__ Wv,
    u16* __restrict__ Qp, u16* __restrict__ Kp, u16* __restrict__ Vp)
{
  int which = blockIdx.y;
  const float* X = which == 0 ? Xq : (which == 1 ? Xk : Xv);
  const float* W = which == 0 ? Wq : (which == 1 ? Wk : Wv);
  u16* Out = which == 0 ? Qp : (which == 1 ? Kp : Vp);
  float wscale = which == 0 ? 0.03125f : 1.0f;

  int t = threadIdx.x;
  int w = t >> 6, l = t & 63, l15 = l & 15, grp = l >> 4;
  int g0 = blockIdx.x * 64;

  // B-frags from W fp32 [64][64]: lane holds W[col=nt*16+l15][k=dc*32+grp*8+j]
  bf16x8 wf[4][2];
#pragma unroll
  for (int nt = 0; nt < 4; nt++) {
    int c = nt * 16 + l15;
#pragma unroll
    for (int dc = 0; dc < 2; dc++) {
      const float* p = W + c * 64 + dc * 32 + grp * 8;
      f32x4 a = *(const f32x4*)p;
      f32x4 b = *(const f32x4*)(p + 4);
      a *= wscale; b *= wscale;
      wf[nt][dc] = cvt8(a, b);
    }
  }
  // A-frags: lane holds X[row=l15][k=dc*32+grp*8+j]
  int grow = g0 + w * 16 + l15;
  const float* xr = X + (long)grow * 64;
  bf16x8 af[2];
#pragma unroll
  for (int dc = 0; dc < 2; dc++) {
    f32x4 a = *(const f32x4*)(xr + dc * 32 + grp * 8);
    f32x4 b = *(const f32x4*)(xr + dc * 32 + grp * 8 + 4);
    af[dc] = cvt8(a, b);
  }
  f32x4 acc[4] = {};
#pragma unroll
  for (int dc = 0; dc < 2; dc++)
#pragma unroll
    for (int nt = 0; nt < 4; nt++)
      acc[nt] = mfma16(af[dc], wf[nt][dc], acc[nt]);

  // D: row=grp*4+r (local), col=nt*16+l15
#pragma unroll
  for (int r = 0; r < 4; r++) {
    int g = g0 + w * 16 + grp * 4 + r;
    int n = g >> 15;          // /(S*H)=32768
    int s = (g >> 4) & 2047;
    int h = g & 15;
    u16* orow = Out + (((long)(n * NHEADS + h) * SEQ + s) << 6);
#pragma unroll
    for (int nt = 0; nt < 4; nt++)
      orow[nt * 16 + l15] = f2bf(acc[nt][r]);
  }
}

// ---------------------------------------------------------------------------
// V transpose: Vp [NH][S][64] -> Vt [NH][64][S]. 64x64 tiles.
__global__ __launch_bounds__(256) void transpose_v(
    const u16* __restrict__ Vp, u16* __restrict__ Vt)
{
  int st = blockIdx.x;  // s-tile (32)
  int nh = blockIdx.y;  // 64
  __shared__ u16 Vs[64 * 65];
  int t = threadIdx.x;
  const u16* src = Vp + ((long)nh * SEQ + st * 64) * 64;
#pragma unroll
  for (int p = 0; p < 2; p++) {
    int row = p * 32 + (t >> 3);
    int c0 = (t & 7) * 8;
    u32x4 u = *(const u32x4*)(src + row * 64 + c0);
    u16x8 v = __builtin_bit_cast(u16x8, u);
#pragma unroll
    for (int j = 0; j < 8; j++) Vs[(c0 + j) * 65 + row] = v[j];
  }
  __syncthreads();
  int e = t >> 2, k0 = (t & 3) * 16;
  u16x8 lo, hi;
#pragma unroll
  for (int j = 0; j < 8; j++) { lo[j] = Vs[e * 65 + k0 + j]; hi[j] = Vs[e * 65 + k0 + 8 + j]; }
  u16* dst = Vt + ((long)nh * 64 + e) * SEQ + st * 64 + k0;
  *(u32x4*)dst = __builtin_bit_cast(u32x4, lo);
  *(u32x4*)(dst + 8) = __builtin_bit_cast(u32x4, hi);
}

// ---------------------------------------------------------------------------
__global__ __launch_bounds__(256) void conv_wo(
    const float* __restrict__ Wo, u16* __restrict__ Wob)
{
  int i = (blockIdx.x * 256 + threadIdx.x) * 4;
  f32x4 v = *(const f32x4*)(Wo + i);
  u64 pk = (u64)f2bf(v[0]) | ((u64)f2bf(v[1]) << 16) |
           ((u64)f2bf(v[2]) << 32) | ((u64)f2bf(v[3]) << 48);
  *(u64*)(Wob + i) = pk;
}

// ---------------------------------------------------------------------------
// Flash attention. Block=(q-tile 64 rows, nh). 4 waves x 16 q-rows.
// K/V 64x64 bf16 tiles in LDS, XOR-swizzled (chunk ^= row&7) -> ~2-way reads.
__global__ __launch_bounds__(256) void attn_kernel(
    const u16* __restrict__ Qp, const u16* __restrict__ Kp, const u16* __restrict__ Vt,
    u16* __restrict__ AO)
{
  int qt = blockIdx.x;  // 32
  int nh = blockIdx.y;  // 64
  int n = nh >> 4, h = nh & 15;
  __shared__ __align__(16) u16 Ks[4096];
  __shared__ __align__(16) u16 Vs[4096];
  __shared__ __align__(16) u16 Ps[4][16 * 72];
  int t = threadIdx.x, w = t >> 6, l = t & 63, l15 = l & 15, grp = l >> 4;

  // Q frags (1/32 already folded into Wq)
  const u16* qrow = Qp + ((long)nh * SEQ + qt * 64 + w * 16 + l15) * 64;
  bf16x8 qf[2];
  qf[0] = __builtin_bit_cast(bf16x8, *(const u32x4*)(qrow + grp * 8));
  qf[1] = __builtin_bit_cast(bf16x8, *(const u32x4*)(qrow + 32 + grp * 8));

  f32x4 Oacc[4] = {};
  float mrun[4], lrun[4];
#pragma unroll
  for (int r = 0; r < 4; r++) { mrun[r] = -1e30f; lrun[r] = 0.f; }

  const char* Kg = (const char*)(Kp + (long)nh * SEQ * 64);
  const char* Vg = (const char*)(Vt + (long)nh * 64 * SEQ);
  char* KsB = (char*)Ks;
  char* VsB = (char*)Vs;
  u16* Pw = Ps[w];

  u32x4 kreg[2], vreg[2];
  // prologue loads (tile 0)
#pragma unroll
  for (int p = 0; p < 2; p++) {
    int chunk = p * 256 + t;
    int row = chunk >> 3, c = chunk & 7;
    kreg[p] = *(const u32x4*)(Kg + row * 128 + c * 16);
    vreg[p] = *(const u32x4*)(Vg + (long)row * 4096 + c * 16);
  }

  for (int kt = 0; kt < 32; kt++) {
    __syncthreads();  // previous tile fully consumed
#pragma unroll
    for (int p = 0; p < 2; p++) {
      int chunk = p * 256 + t;
      int row = chunk >> 3, c = chunk & 7;
      int phys = row * 128 + ((c ^ (row & 7)) << 4);
      *(u32x4*)(KsB + phys) = kreg[p];
      *(u32x4*)(VsB + phys) = vreg[p];
    }
    __syncthreads();
    if (kt + 1 < 32) {  // prefetch next tile into regs (overlaps compute)
#pragma unroll
      for (int p = 0; p < 2; p++) {
        int chunk = p * 256 + t;
        int row = chunk >> 3, c = chunk & 7;
        kreg[p] = *(const u32x4*)(Kg + (long)(kt + 1) * 8192 + row * 128 + c * 16);
        vreg[p] = *(const u32x4*)(Vg + (long)row * 4096 + (kt + 1) * 128 + c * 16);
      }
    }

    // QK^T: S[q=16][kidx=64]
    f32x4 sacc[4];
#pragma unroll
    for (int nt = 0; nt < 4; nt++) sacc[nt] = (f32x4){0.f, 0.f, 0.f, 0.f};
#pragma unroll
    for (int dc = 0; dc < 2; dc++) {
#pragma unroll
      for (int nt = 0; nt < 4; nt++) {
        int kr = nt * 16 + l15;
        int cl = dc * 4 + grp;
        bf16x8 kf = __builtin_bit_cast(bf16x8,
            *(const u32x4*)(KsB + kr * 128 + ((cl ^ (kr & 7)) << 4)));
        sacc[nt] = mfma16(qf[dc], kf, sacc[nt]);
      }
    }

    // online softmax (rows: grp*4+r; reduce over 16 lanes of l15 + 4 nt)
    float mnew[4], scl[4], psum[4];
#pragma unroll
    for (int r = 0; r < 4; r++) {
      float m = fmaxf(fmaxf(sacc[0][r], sacc[1][r]), fmaxf(sacc[2][r], sacc[3][r]));
#pragma unroll
      for (int off = 1; off < 16; off <<= 1) m = fmaxf(m, __shfl_xor(m, off));
      mnew[r] = fmaxf(mrun[r], m);
      scl[r] = __expf(mrun[r] - mnew[r]);
      psum[r] = 0.f;
    }
#pragma unroll
    for (int nt = 0; nt < 4; nt++) {
#pragma unroll
      for (int r = 0; r < 4; r++) {
        float p = __expf(sacc[nt][r] - mnew[r]);
        psum[r] += p;
        Pw[(grp * 4 + r) * 72 + nt * 16 + l15] = f2bf(p);
      }
    }
#pragma unroll
    for (int r = 0; r < 4; r++) {
      float s = psum[r];
#pragma unroll
      for (int off = 1; off < 16; off <<= 1) s += __shfl_xor(s, off);
      lrun[r] = lrun[r] * scl[r] + s;
      mrun[r] = mnew[r];
    }
#pragma unroll
    for (int et = 0; et < 4; et++) {
      f32x4 o = Oacc[et];
#pragma unroll
      for (int r = 0; r < 4; r++) o[r] *= scl[r];
      Oacc[et] = o;
    }

    // PV: A=P[q=l15][k], B=Vt[e=l15][k]
#pragma unroll
    for (int kc = 0; kc < 2; kc++) {
      bf16x8 pf = __builtin_bit_cast(bf16x8,
          *(const u32x4*)((const char*)Pw + l15 * 144 + kc * 64 + grp * 16));
#pragma unroll
      for (int et = 0; et < 4; et++) {
        int er = et * 16 + l15;
        int cl = kc * 4 + grp;
        bf16x8 vf = __builtin_bit_cast(bf16x8,
            *(const u32x4*)(VsB + er * 128 + ((cl ^ (er & 7)) << 4)));
        Oacc[et] = mfma16(pf, vf, Oacc[et]);
      }
    }
  }

  // epilogue: O/l, write AO [N][S][E] bf16
  int s_base = qt * 64 + w * 16;
#pragma unroll
  for (int r = 0; r < 4; r++) {
    int srow = s_base + grp * 4 + r;
    float inv = 1.0f / lrun[r];
    u16* orow = AO + ((long)(n * SEQ + srow)) * EMB + h * 64;
#pragma unroll
    for (int et = 0; et < 4; et++)
      orow[et * 16 + l15] = f2bf(Oacc[et][r] * inv);
  }
}

// ---------------------------------------------------------------------------
// Output GEMM: C[8192][1024] = AO[8192][1024] @ Wob[1024][1024]^T + bo, fp32 out.
// 128x128 tile, BK=32, 4 waves (2x2), 4x4 16x16 accs per wave.
__global__ __launch_bounds__(256) void gemm_out(
    const u16* __restrict__ A, const u16* __restrict__ B,
    const float* __restrict__ bias, float* __restrict__ C)
{
  int bm = blockIdx.x, bn = blockIdx.y;
  __shared__ __align__(16) u16 As[4096];
  __shared__ __align__(16) u16 Bs[4096];
  int t = threadIdx.x, w = t >> 6, l = t & 63, l15 = l & 15, grp = l >> 4;
  int wm = w >> 1, wn = w & 1;
  f32x4 acc[4][4] = {};
  const char* Ab = (const char*)(A + (long)bm * 128 * 1024);
  const char* Bb = (const char*)(B + (long)bn * 128 * 1024);
  char* AsB = (char*)As;
  char* BsB = (char*)Bs;

  u32x4 areg[2], breg[2];
#pragma unroll
  for (int p = 0; p < 2; p++) {
    int chunk = p * 256 + t;
    int row = chunk >> 2, c = chunk & 3;
    areg[p] = *(const u32x4*)(Ab + (long)row * 2048 + c * 16);
    breg[p] = *(const u32x4*)(Bb + (long)row * 2048 + c * 16);
  }

  for (int kt = 0; kt < 32; kt++) {
    __syncthreads();
#pragma unroll
    for (int p = 0; p < 2; p++) {
      int chunk = p * 256 + t;
      int row = chunk >> 2, c = chunk & 3;
      int phys = row * 64 + ((c ^ ((row >> 1) & 3)) << 4);
      *(u32x4*)(AsB + phys) = areg[p];
      *(u32x4*)(BsB + phys) = breg[p];
    }
    __syncthreads();
    if (kt + 1 < 32) {
#pragma unroll
      for (int p = 0; p < 2; p++) {
        int chunk = p * 256 + t;
        int row = chunk >> 2, c = chunk & 3;
        areg[p] = *(const u32x4*)(Ab + (long)row * 2048 + (kt + 1) * 64 + c * 16);
        breg[p] = *(const u32x4*)(Bb + (long)row * 2048 + (kt + 1) * 64 + c * 16);
      }
    }
    bf16x8 af[4], bf_[4];
#pragma unroll
    for (int i = 0; i < 4; i++) {
      int row = wm * 64 + i * 16 + l15;
      af[i] = __builtin_bit_cast(bf16x8,
          *(const u32x4*)(AsB + row * 64 + ((grp ^ ((row >> 1) & 3)) << 4)));
      int rowb = wn * 64 + i * 16 + l15;
      bf_[i] = __builtin_bit_cast(bf16x8,
          *(const u32x4*)(BsB + rowb * 64 + ((grp ^ ((rowb >> 1) & 3)) << 4)));
    }
#pragma unroll
    for (int i = 0; i < 4; i++)
#pragma unroll
      for (int j = 0; j < 4; j++)
        acc[i][j] = mfma16(af[i], bf_[j], acc[i][j]);
  }

  float bv[4];
#pragma unroll
  for (int j = 0; j < 4; j++) bv[j] = bias[bn * 128 + wn * 64 + j * 16 + l15];
#pragma unroll
  for (int i = 0; i < 4; i++) {
#pragma unroll
    for (int r = 0; r < 4; r++) {
      long row = (long)bm * 128 + wm * 64 + i * 16 + grp * 4 + r;
      float* crow = C + row * 1024 + bn * 128 + wn * 64;
#pragma unroll
      for (int j = 0; j < 4; j++)
        crow[j * 16 + l15] = acc[i][j][r] + bv[j];
    }
  }
}

// ---------------------------------------------------------------------------
extern "C" void kernel_launch(void* const* d_in, const int* in_sizes, int n_in,
                              void* d_out, int out_size, void* d_ws, size_t ws_size,
                              hipStream_t stream)
{
  const float* Vx = (const float*)d_in[0];
  const float* Kx = (const float*)d_in[1];
  const float* Qx = (const float*)d_in[2];
  // d_in[3] = mask (unused by reference forward)
  const float* Wv = (const float*)d_in[4];
  const float* Wk = (const float*)d_in[5];
  const float* Wq = (const float*)d_in[6];
  const float* Wo = (const float*)d_in[7];
  const float* bo = (const float*)d_in[8];
  float* out = (float*)d_out;
  char* ws = (char*)d_ws;

  u16* Qp  = (u16*)(ws);
  u16* Kp  = (u16*)(ws + (1L << 24));
  u16* Vt  = (u16*)(ws + (2L << 24));
  u16* Vp  = (u16*)(ws + (3L << 24));  // reused as AO after transpose
  u16* AO  = Vp;
  u16* Wob = (u16*)(ws + (4L << 24));

  proj_kernel<<<dim3(2048, 3), 256, 0, stream>>>(Qx, Kx, Vx, Wq, Wk, Wv, Qp, Kp, Vp);
  transpose_v<<<dim3(32, 64), 256, 0, stream>>>(Vp, Vt);
  conv_wo<<<1024, 256, 0, stream>>>(Wo, Wob);
  attn_kernel<<<dim3(32, 64), 256, 0, stream>>>(Qp, Kp, Vt, AO);
  gemm_out<<<dim3(64, 8), 256, 0, stream>>>(AO, Wob, bo, out);
}

// Round 3
// 198.926 us; speedup vs baseline: 1.4870x; 1.4870x over previous
//
#include <hip/hip_runtime.h>

// MultiHeadSelfAttention: N=4 S=2048 E=1024 H=16 D=64
// Pipeline: proj(QKV, bf16 MFMA) -> transpose V -> conv Wo -> flash attn -> out GEMM
// Round 3: attn rewritten as 4-warp 32x32 swapped-QK^T flash attention with
// in-register softmax (T12: cvt_pk_bf16 + permlane32_swap), exp2-space scores
// (log2e/32 folded into Wq), s_setprio around MFMA clusters (T5).
//
// Workspace layout:
//   Qp [NH][S][64] bf16 @ 0
//   Kp [NH][S][64] bf16 @ 16 MiB
//   Vt [NH][64][S] bf16 @ 32 MiB
//   Vp [NH][S][64] bf16 @ 48 MiB  (reused as AO [N][S][E] bf16 after transpose)
//   Wob [1024][1024] bf16 @ 64 MiB

using f32x4  = __attribute__((ext_vector_type(4))) float;
using f32x16 = __attribute__((ext_vector_type(16))) float;
using bf16x8 = __attribute__((ext_vector_type(8))) __bf16;
using u32x4  = __attribute__((ext_vector_type(4))) unsigned int;
using u16x8  = __attribute__((ext_vector_type(8))) unsigned short;
typedef unsigned short u16;
typedef unsigned int   u32;
typedef unsigned long long u64;

#define SEQ 2048
#define EMB 1024
#define NHEADS 16
#define HDIM 64
#define NBATCH 4
#define NH 64  // NBATCH*NHEADS

__device__ __forceinline__ u16 f2bf(float f) {
  u32 u = __builtin_bit_cast(u32, f);
  return (u16)((u + 0x7fffu + ((u >> 16) & 1u)) >> 16);
}

__device__ __forceinline__ f32x4 mfma16(bf16x8 a, bf16x8 b, f32x4 c) {
  return __builtin_amdgcn_mfma_f32_16x16x32_bf16(a, b, c, 0, 0, 0);
}

__device__ __forceinline__ f32x16 mfma32(bf16x8 a, bf16x8 b, f32x16 c) {
  return __builtin_amdgcn_mfma_f32_32x32x16_bf16(a, b, c, 0, 0, 0);
}

__device__ __forceinline__ bf16x8 cvt8(f32x4 a, f32x4 b) {
  u16x8 r;
  r[0] = f2bf(a[0]); r[1] = f2bf(a[1]); r[2] = f2bf(a[2]); r[3] = f2bf(a[3]);
  r[4] = f2bf(b[0]); r[5] = f2bf(b[1]); r[6] = f2bf(b[2]); r[7] = f2bf(b[3]);
  return __builtin_bit_cast(bf16x8, r);
}

// pack two f32 -> one u32 of 2 bf16 (elem0 in low16), RTNE
__device__ __forceinline__ u32 cvtpk_bf16(float a, float b) {
  u32 d;
  asm("v_cvt_pk_bf16_f32 %0, %1, %2" : "=v"(d) : "v"(a), "v"(b));
  return d;
}

__device__ __forceinline__ float fexp2(float x) {
#if __has_builtin(__builtin_amdgcn_exp2f)
  return __builtin_amdgcn_exp2f(x);
#else
  return __expf(x * 0.6931471805599453f);
#endif
}

// wlo = [a.lanes0-31, b.lanes0-31], whi = [a.lanes32-63, b.lanes32-63]
__device__ __forceinline__ void swap_words(u32 a, u32 b, int hi, u32& wlo, u32& whi) {
#if __has_builtin(__builtin_amdgcn_permlane32_swap)
  (void)hi;
  auto rr = __builtin_amdgcn_permlane32_swap((int)a, (int)b, false, false);
  wlo = (u32)rr[0];
  whi = (u32)rr[1];
#else
  u32 pa = (u32)__shfl_xor((int)a, 32);
  u32 pb = (u32)__shfl_xor((int)b, 32);
  wlo = hi ? pb : a;
  whi = hi ? b : pa;
#endif
}

// ---------------------------------------------------------------------------
// Projection: per-head y = x @ W^T, X rows g=(n*S+s)*H+h are contiguous [64].
// Out = [NH][S][64] bf16. Wq pre-scaled by log2(e)/32 (exp2-space softmax).
__global__ __launch_bounds__(256) void proj_kernel(
    const float* __restrict__ Xq, const float* __restrict__ Xk, const float* __restrict__ Xv,
    const float* __restrict__ Wq, const float* __restrict__ Wk, const float* __restrict__ Wv,
    u16* __restrict__ Qp, u16* __restrict__ Kp, u16* __restrict__ Vp)
{
  int which = blockIdx.y;
  const float* X = which == 0 ? Xq : (which == 1 ? Xk : Xv);
  const float* W = which == 0 ? Wq : (which == 1 ? Wk : Wv);
  u16* Out = which == 0 ? Qp : (which == 1 ? Kp : Vp);
  float wscale = which == 0 ? 0.045084220027780106f : 1.0f;  // log2e/32

  int t = threadIdx.x;
  int w = t >> 6, l = t & 63, l15 = l & 15, grp = l >> 4;
  int g0 = blockIdx.x * 64;

  bf16x8 wf[4][2];
#pragma unroll
  for (int nt = 0; nt < 4; nt++) {
    int c = nt * 16 + l15;
#pragma unroll
    for (int dc = 0; dc < 2; dc++) {
      const float* p = W + c * 64 + dc * 32 + grp * 8;
      f32x4 a = *(const f32x4*)p;
      f32x4 b = *(const f32x4*)(p + 4);
      a *= wscale; b *= wscale;
      wf[nt][dc] = cvt8(a, b);
    }
  }
  int grow = g0 + w * 16 + l15;
  const float* xr = X + (long)grow * 64;
  bf16x8 af[2];
#pragma unroll
  for (int dc = 0; dc < 2; dc++) {
    f32x4 a = *(const f32x4*)(xr + dc * 32 + grp * 8);
    f32x4 b = *(const f32x4*)(xr + dc * 32 + grp * 8 + 4);
    af[dc] = cvt8(a, b);
  }
  f32x4 acc[4] = {};
#pragma unroll
  for (int dc = 0; dc < 2; dc++)
#pragma unroll
    for (int nt = 0; nt < 4; nt++)
      acc[nt] = mfma16(af[dc], wf[nt][dc], acc[nt]);

#pragma unroll
  for (int r = 0; r < 4; r++) {
    int g = g0 + w * 16 + grp * 4 + r;
    int n = g >> 15;
    int s = (g >> 4) & 2047;
    int h = g & 15;
    u16* orow = Out + (((long)(n * NHEADS + h) * SEQ + s) << 6);
#pragma unroll
    for (int nt = 0; nt < 4; nt++)
      orow[nt * 16 + l15] = f2bf(acc[nt][r]);
  }
}

// ---------------------------------------------------------------------------
// V transpose: Vp [NH][S][64] -> Vt [NH][64][S]. 64x64 tiles.
__global__ __launch_bounds__(256) void transpose_v(
    const u16* __restrict__ Vp, u16* __restrict__ Vt)
{
  int st = blockIdx.x;
  int nh = blockIdx.y;
  __shared__ u16 Vs[64 * 65];
  int t = threadIdx.x;
  const u16* src = Vp + ((long)nh * SEQ + st * 64) * 64;
#pragma unroll
  for (int p = 0; p < 2; p++) {
    int row = p * 32 + (t >> 3);
    int c0 = (t & 7) * 8;
    u32x4 u = *(const u32x4*)(src + row * 64 + c0);
    u16x8 v = __builtin_bit_cast(u16x8, u);
#pragma unroll
    for (int j = 0; j < 8; j++) Vs[(c0 + j) * 65 + row] = v[j];
  }
  __syncthreads();
  int e = t >> 2, k0 = (t & 3) * 16;
  u16x8 lo, hi;
#pragma unroll
  for (int j = 0; j < 8; j++) { lo[j] = Vs[e * 65 + k0 + j]; hi[j] = Vs[e * 65 + k0 + 8 + j]; }
  u16* dst = Vt + ((long)nh * 64 + e) * SEQ + st * 64 + k0;
  *(u32x4*)dst = __builtin_bit_cast(u32x4, lo);
  *(u32x4*)(dst + 8) = __builtin_bit_cast(u32x4, hi);
}

// ---------------------------------------------------------------------------
__global__ __launch_bounds__(256) void conv_wo(
    const float* __restrict__ Wo, u16* __restrict__ Wob)
{
  int i = (blockIdx.x * 256 + threadIdx.x) * 4;
  f32x4 v = *(const f32x4*)(Wo + i);
  u64 pk = (u64)f2bf(v[0]) | ((u64)f2bf(v[1]) << 16) |
           ((u64)f2bf(v[2]) << 32) | ((u64)f2bf(v[3]) << 48);
  *(u64*)(Wob + i) = pk;
}

// ---------------------------------------------------------------------------
// Flash attention, 4 warps x 32 q-rows (128 q/block), KVBLK=64, 32x32x16 MFMA.
// Swapped QK^T: S^T = K·Q^T so each lane owns one q-row (col = lane&31).
// P stays in registers: cvt_pk_bf16 + permlane32_swap -> PV B-frags directly.
// K/V tiles in XOR-swizzled LDS ([row][128B], chunk ^= row&7): conflict-free.
__global__ __launch_bounds__(256, 3) void attn_kernel(
    const u16* __restrict__ Qp, const u16* __restrict__ Kp, const u16* __restrict__ Vt,
    u16* __restrict__ AO)
{
  int nh = blockIdx.x;  // 0..63 (x=nh: q-blocks of a head share an XCD)
  int qb = blockIdx.y;  // 0..15
  int n = nh >> 4, h = nh & 15;

  __shared__ __align__(16) char smem[128 * 144];  // main: Ks[0:8K) Vs[8K:16K); epi: Osm
  char* KsB = smem;
  char* VsB = smem + 8192;

  int t = threadIdx.x, w = t >> 6, l = t & 63;
  int l31 = l & 31, hi = l >> 5;

  // Q as MFMA B-frag: lane holds Q[qrow=l31][d = dc*16 + hi*8 + j]
  long qrow = (long)nh * SEQ + qb * 128 + w * 32 + l31;
  const char* qbase = (const char*)Qp + qrow * 128;
  bf16x8 qf[4];
#pragma unroll
  for (int dc = 0; dc < 4; dc++)
    qf[dc] = __builtin_bit_cast(bf16x8, *(const u32x4*)(qbase + dc * 32 + hi * 16));

  f32x16 o0 = {}, o1 = {};  // O^T: C[e][q], e 0-31 / 32-63
  float mrun = -1e30f, lrun = 0.f;

  const char* Kg = (const char*)(Kp + (long)nh * SEQ * 64);
  const char* Vg = (const char*)(Vt + (long)nh * 64 * SEQ);

  u32x4 kreg[2], vreg[2];
#pragma unroll
  for (int p = 0; p < 2; p++) {
    int chunk = p * 256 + t;
    int row = chunk >> 3, c = chunk & 7;
    kreg[p] = *(const u32x4*)(Kg + row * 128 + c * 16);
    vreg[p] = *(const u32x4*)(Vg + (long)row * 4096 + c * 16);
  }

  for (int kt = 0; kt < 32; kt++) {
    __syncthreads();  // previous tile fully consumed
#pragma unroll
    for (int p = 0; p < 2; p++) {
      int chunk = p * 256 + t;
      int row = chunk >> 3, c = chunk & 7;
      int phys = row * 128 + ((c ^ (row & 7)) << 4);
      *(u32x4*)(KsB + phys) = kreg[p];
      *(u32x4*)(VsB + phys) = vreg[p];
    }
    __syncthreads();
    if (kt + 1 < 32) {  // prefetch next tile into regs (hides under compute)
#pragma unroll
      for (int p = 0; p < 2; p++) {
        int chunk = p * 256 + t;
        int row = chunk >> 3, c = chunk & 7;
        kreg[p] = *(const u32x4*)(Kg + (long)(kt + 1) * 8192 + row * 128 + c * 16);
        vreg[p] = *(const u32x4*)(Vg + (long)row * 4096 + (kt + 1) * 128 + c * 16);
      }
    }

    // QK^T swapped: two C-tiles S^T[kidx 0-31 / 32-63][q]
    f32x16 s0 = {}, s1 = {};
    __builtin_amdgcn_s_setprio(1);
#pragma unroll
    for (int dc = 0; dc < 4; dc++) {
      int cc = dc * 2 + hi;
      int r0 = l31;
      bf16x8 kf0 = __builtin_bit_cast(bf16x8,
          *(const u32x4*)(KsB + r0 * 128 + ((cc ^ (r0 & 7)) << 4)));
      s0 = mfma32(kf0, qf[dc], s0);
      int r1 = 32 + l31;
      bf16x8 kf1 = __builtin_bit_cast(bf16x8,
          *(const u32x4*)(KsB + r1 * 128 + ((cc ^ (r1 & 7)) << 4)));
      s1 = mfma32(kf1, qf[dc], s1);
    }
    __builtin_amdgcn_s_setprio(0);

    // in-register online softmax (exp2-space; log2e/32 folded into Wq)
    float mx = -1e30f;
#pragma unroll
    for (int r = 0; r < 8; r++)
      mx = fmaxf(mx, fmaxf(fmaxf(s0[2*r], s0[2*r+1]), fmaxf(s1[2*r], s1[2*r+1])));
    mx = fmaxf(mx, __shfl_xor(mx, 32));
    float mnew = fmaxf(mrun, mx);
    float scl = fexp2(mrun - mnew);
    mrun = mnew;
    lrun *= scl;
#pragma unroll
    for (int r = 0; r < 16; r++) { s0[r] = fexp2(s0[r] - mnew); lrun += s0[r]; }
#pragma unroll
    for (int r = 0; r < 16; r++) { s1[r] = fexp2(s1[r] - mnew); lrun += s1[r]; }
#pragma unroll
    for (int r = 0; r < 16; r++) { o0[r] *= scl; o1[r] *= scl; }

    // pack P^T into PV B-frags: 16 cvt_pk + 8 permlane32_swap
    bf16x8 pB[4];
    {
      u32 xw[8], wq[16];
#pragma unroll
      for (int i = 0; i < 8; i++) xw[i] = cvtpk_bf16(s0[2*i], s0[2*i+1]);
      swap_words(xw[0], xw[2], hi, wq[0],  wq[2]);
      swap_words(xw[1], xw[3], hi, wq[1],  wq[3]);
      swap_words(xw[4], xw[6], hi, wq[4],  wq[6]);
      swap_words(xw[5], xw[7], hi, wq[5],  wq[7]);
#pragma unroll
      for (int i = 0; i < 8; i++) xw[i] = cvtpk_bf16(s1[2*i], s1[2*i+1]);
      swap_words(xw[0], xw[2], hi, wq[8],  wq[10]);
      swap_words(xw[1], xw[3], hi, wq[9],  wq[11]);
      swap_words(xw[4], xw[6], hi, wq[12], wq[14]);
      swap_words(xw[5], xw[7], hi, wq[13], wq[15]);
#pragma unroll
      for (int kb = 0; kb < 4; kb++) {
        u32x4 v4 = { wq[kb*4+0], wq[kb*4+1], wq[kb*4+2], wq[kb*4+3] };
        pB[kb] = __builtin_bit_cast(bf16x8, v4);
      }
    }

    // PV: O^T += V^T · P^T
    __builtin_amdgcn_s_setprio(1);
#pragma unroll
    for (int kb = 0; kb < 4; kb++) {
      int cc = kb * 2 + hi;
      int r0 = l31;
      bf16x8 vf0 = __builtin_bit_cast(bf16x8,
          *(const u32x4*)(VsB + r0 * 128 + ((cc ^ (r0 & 7)) << 4)));
      o0 = mfma32(vf0, pB[kb], o0);
      int r1 = 32 + l31;
      bf16x8 vf1 = __builtin_bit_cast(bf16x8,
          *(const u32x4*)(VsB + r1 * 128 + ((cc ^ (r1 & 7)) << 4)));
      o1 = mfma32(vf1, pB[kb], o1);
    }
    __builtin_amdgcn_s_setprio(0);
  }

  // epilogue: normalize, transpose via LDS, coalesced bf16 store to AO
  __syncthreads();  // done with Ks/Vs
  lrun += __shfl_xor(lrun, 32);
  float inv = 1.0f / lrun;
  int qlocal = w * 32 + l31;
  char* OsmB = smem;  // [128 q][72 u16] rows (144B, 16-aligned)
#pragma unroll
  for (int i = 0; i < 8; i++) {
    int e0 = ((2*i) & 3) + 8 * ((2*i) >> 2) + 4 * hi;  // e for reg 2i (pair e0,e0+1)
    u32 pk0 = cvtpk_bf16(o0[2*i] * inv, o0[2*i+1] * inv);
    *(u32*)(OsmB + qlocal * 144 + 2 * e0) = pk0;
    u32 pk1 = cvtpk_bf16(o1[2*i] * inv, o1[2*i+1] * inv);
    *(u32*)(OsmB + qlocal * 144 + 2 * (e0 + 32)) = pk1;
  }
  __syncthreads();
  int qr = t >> 1, half = t & 1;
  const char* src = OsmB + qr * 144 + half * 64;
  long qg = (long)qb * 128 + qr;
  char* dst = (char*)(AO + ((long)n * SEQ + qg) * EMB + h * 64 + half * 32);
#pragma unroll
  for (int j = 0; j < 4; j++)
    *(u32x4*)(dst + j * 16) = *(const u32x4*)(src + j * 16);
}

// ---------------------------------------------------------------------------
// Output GEMM: C[8192][1024] = AO[8192][1024] @ Wob[1024][1024]^T + bo, fp32 out.
__global__ __launch_bounds__(256) void gemm_out(
    const u16* __restrict__ A, const u16* __restrict__ B,
    const float* __restrict__ bias, float* __restrict__ C)
{
  int bm = blockIdx.x, bn = blockIdx.y;
  __shared__ __align__(16) u16 As[4096];
  __shared__ __align__(16) u16 Bs[4096];
  int t = threadIdx.x, w = t >> 6, l = t & 63, l15 = l & 15, grp = l >> 4;
  int wm = w >> 1, wn = w & 1;
  f32x4 acc[4][4] = {};
  const char* Ab = (const char*)(A + (long)bm * 128 * 1024);
  const char* Bb = (const char*)(B + (long)bn * 128 * 1024);
  char* AsB = (char*)As;
  char* BsB = (char*)Bs;

  u32x4 areg[2], breg[2];
#pragma unroll
  for (int p = 0; p < 2; p++) {
    int chunk = p * 256 + t;
    int row = chunk >> 2, c = chunk & 3;
    areg[p] = *(const u32x4*)(Ab + (long)row * 2048 + c * 16);
    breg[p] = *(const u32x4*)(Bb + (long)row * 2048 + c * 16);
  }

  for (int kt = 0; kt < 32; kt++) {
    __syncthreads();
#pragma unroll
    for (int p = 0; p < 2; p++) {
      int chunk = p * 256 + t;
      int row = chunk >> 2, c = chunk & 3;
      int phys = row * 64 + ((c ^ ((row >> 1) & 3)) << 4);
      *(u32x4*)(AsB + phys) = areg[p];
      *(u32x4*)(BsB + phys) = breg[p];
    }
    __syncthreads();
    if (kt + 1 < 32) {
#pragma unroll
      for (int p = 0; p < 2; p++) {
        int chunk = p * 256 + t;
        int row = chunk >> 2, c = chunk & 3;
        areg[p] = *(const u32x4*)(Ab + (long)row * 2048 + (kt + 1) * 64 + c * 16);
        breg[p] = *(const u32x4*)(Bb + (long)row * 2048 + (kt + 1) * 64 + c * 16);
      }
    }
    bf16x8 af[4], bf_[4];
#pragma unroll
    for (int i = 0; i < 4; i++) {
      int row = wm * 64 + i * 16 + l15;
      af[i] = __builtin_bit_cast(bf16x8,
          *(const u32x4*)(AsB + row * 64 + ((grp ^ ((row >> 1) & 3)) << 4)));
      int rowb = wn * 64 + i * 16 + l15;
      bf_[i] = __builtin_bit_cast(bf16x8,
          *(const u32x4*)(BsB + rowb * 64 + ((grp ^ ((rowb >> 1) & 3)) << 4)));
    }
#pragma unroll
    for (int i = 0; i < 4; i++)
#pragma unroll
      for (int j = 0; j < 4; j++)
        acc[i][j] = mfma16(af[i], bf_[j], acc[i][j]);
  }

  float bv[4];
#pragma unroll
  for (int j = 0; j < 4; j++) bv[j] = bias[bn * 128 + wn * 64 + j * 16 + l15];
#pragma unroll
  for (int i = 0; i < 4; i++) {
#pragma unroll
    for (int r = 0; r < 4; r++) {
      long row = (long)bm * 128 + wm * 64 + i * 16 + grp * 4 + r;
      float* crow = C + row * 1024 + bn * 128 + wn * 64;
#pragma unroll
      for (int j = 0; j < 4; j++)
        crow[j * 16 + l15] = acc[i][j][r] + bv[j];
    }
  }
}

// ---------------------------------------------------------------------------
extern "C" void kernel_launch(void* const* d_in, const int* in_sizes, int n_in,
                              void* d_out, int out_size, void* d_ws, size_t ws_size,
                              hipStream_t stream)
{
  const float* Vx = (const float*)d_in[0];
  const float* Kx = (const float*)d_in[1];
  const float* Qx = (const float*)d_in[2];
  // d_in[3] = mask (unused by reference forward)
  const float* Wv = (const float*)d_in[4];
  const float* Wk = (const float*)d_in[5];
  const float* Wq = (const float*)d_in[6];
  const float* Wo = (const float*)d_in[7];
  const float* bo = (const float*)d_in[8];
  float* out = (float*)d_out;
  char* ws = (char*)d_ws;

  u16* Qp  = (u16*)(ws);
  u16* Kp  = (u16*)(ws + (1L << 24));
  u16* Vt  = (u16*)(ws + (2L << 24));
  u16* Vp  = (u16*)(ws + (3L << 24));  // reused as AO after transpose
  u16* AO  = Vp;
  u16* Wob = (u16*)(ws + (4L << 24));

  proj_kernel<<<dim3(2048, 3), 256, 0, stream>>>(Qx, Kx, Vx, Wq, Wk, Wv, Qp, Kp, Vp);
  transpose_v<<<dim3(32, 64), 256, 0, stream>>>(Vp, Vt);
  conv_wo<<<1024, 256, 0, stream>>>(Wo, Wob);
  attn_kernel<<<dim3(64, 16), 256, 0, stream>>>(Qp, Kp, Vt, AO);
  gemm_out<<<dim3(64, 8), 256, 0, stream>>>(AO, Wob, bo, out);
}

// Round 4
// 189.959 us; speedup vs baseline: 1.5572x; 1.0472x over previous
//
#include <hip/hip_runtime.h>

// MultiHeadSelfAttention: N=4 S=2048 E=1024 H=16 D=64
// Round 4: attn -> double-buffered LDS single-barrier/kt, defer-max (T13),
// tree-reduced row-sum; proj/conv -> v_cvt_pk_bf16_f32; gemm_out -> dbuf
// single-barrier + setprio.
//
// Workspace layout:
//   Qp [NH][S][64] bf16 @ 0
//   Kp [NH][S][64] bf16 @ 16 MiB
//   Vt [NH][64][S] bf16 @ 32 MiB
//   Vp [NH][S][64] bf16 @ 48 MiB  (reused as AO [N][S][E] bf16 after transpose)
//   Wob [1024][1024] bf16 @ 64 MiB

using f32x4  = __attribute__((ext_vector_type(4))) float;
using f32x16 = __attribute__((ext_vector_type(16))) float;
using bf16x8 = __attribute__((ext_vector_type(8))) __bf16;
using u32x4  = __attribute__((ext_vector_type(4))) unsigned int;
using u16x8  = __attribute__((ext_vector_type(8))) unsigned short;
typedef unsigned short u16;
typedef unsigned int   u32;
typedef unsigned long long u64;

#define SEQ 2048
#define EMB 1024
#define NHEADS 16
#define HDIM 64
#define NBATCH 4
#define NH 64  // NBATCH*NHEADS

__device__ __forceinline__ u16 f2bf(float f) {
  u32 u = __builtin_bit_cast(u32, f);
  return (u16)((u + 0x7fffu + ((u >> 16) & 1u)) >> 16);
}

// pack two f32 -> one u32 of 2 bf16 (elem0 in low16), RTNE
__device__ __forceinline__ u32 cvtpk_bf16(float a, float b) {
  u32 d;
  asm("v_cvt_pk_bf16_f32 %0, %1, %2" : "=v"(d) : "v"(a), "v"(b));
  return d;
}

__device__ __forceinline__ f32x4 mfma16(bf16x8 a, bf16x8 b, f32x4 c) {
  return __builtin_amdgcn_mfma_f32_16x16x32_bf16(a, b, c, 0, 0, 0);
}

__device__ __forceinline__ f32x16 mfma32(bf16x8 a, bf16x8 b, f32x16 c) {
  return __builtin_amdgcn_mfma_f32_32x32x16_bf16(a, b, c, 0, 0, 0);
}

__device__ __forceinline__ bf16x8 cvt8(f32x4 a, f32x4 b) {
  u32x4 r;
  r[0] = cvtpk_bf16(a[0], a[1]);
  r[1] = cvtpk_bf16(a[2], a[3]);
  r[2] = cvtpk_bf16(b[0], b[1]);
  r[3] = cvtpk_bf16(b[2], b[3]);
  return __builtin_bit_cast(bf16x8, r);
}

__device__ __forceinline__ float fexp2(float x) {
#if __has_builtin(__builtin_amdgcn_exp2f)
  return __builtin_amdgcn_exp2f(x);
#else
  return __expf(x * 0.6931471805599453f);
#endif
}

// wlo = [a.lanes0-31, b.lanes0-31], whi = [a.lanes32-63, b.lanes32-63]
__device__ __forceinline__ void swap_words(u32 a, u32 b, int hi, u32& wlo, u32& whi) {
#if __has_builtin(__builtin_amdgcn_permlane32_swap)
  (void)hi;
  auto rr = __builtin_amdgcn_permlane32_swap((int)a, (int)b, false, false);
  wlo = (u32)rr[0];
  whi = (u32)rr[1];
#else
  u32 pa = (u32)__shfl_xor((int)a, 32);
  u32 pb = (u32)__shfl_xor((int)b, 32);
  wlo = hi ? pb : a;
  whi = hi ? b : pa;
#endif
}

// ---------------------------------------------------------------------------
// Projection: per-head y = x @ W^T, X rows g=(n*S+s)*H+h are contiguous [64].
// Out = [NH][S][64] bf16. Wq pre-scaled by log2(e)/32 (exp2-space softmax).
__global__ __launch_bounds__(256) void proj_kernel(
    const float* __restrict__ Xq, const float* __restrict__ Xk, const float* __restrict__ Xv,
    const float* __restrict__ Wq, const float* __restrict__ Wk, const float* __restrict__ Wv,
    u16* __restrict__ Qp, u16* __restrict__ Kp, u16* __restrict__ Vp)
{
  int which = blockIdx.y;
  const float* X = which == 0 ? Xq : (which == 1 ? Xk : Xv);
  const float* W = which == 0 ? Wq : (which == 1 ? Wk : Wv);
  u16* Out = which == 0 ? Qp : (which == 1 ? Kp : Vp);
  float wscale = which == 0 ? 0.045084220027780106f : 1.0f;  // log2e/32

  int t = threadIdx.x;
  int w = t >> 6, l = t & 63, l15 = l & 15, grp = l >> 4;
  int g0 = blockIdx.x * 64;

  bf16x8 wf[4][2];
#pragma unroll
  for (int nt = 0; nt < 4; nt++) {
    int c = nt * 16 + l15;
#pragma unroll
    for (int dc = 0; dc < 2; dc++) {
      const float* p = W + c * 64 + dc * 32 + grp * 8;
      f32x4 a = *(const f32x4*)p;
      f32x4 b = *(const f32x4*)(p + 4);
      a *= wscale; b *= wscale;
      wf[nt][dc] = cvt8(a, b);
    }
  }
  int grow = g0 + w * 16 + l15;
  const float* xr = X + (long)grow * 64;
  bf16x8 af[2];
#pragma unroll
  for (int dc = 0; dc < 2; dc++) {
    f32x4 a = *(const f32x4*)(xr + dc * 32 + grp * 8);
    f32x4 b = *(const f32x4*)(xr + dc * 32 + grp * 8 + 4);
    af[dc] = cvt8(a, b);
  }
  f32x4 acc[4] = {};
#pragma unroll
  for (int dc = 0; dc < 2; dc++)
#pragma unroll
    for (int nt = 0; nt < 4; nt++)
      acc[nt] = mfma16(af[dc], wf[nt][dc], acc[nt]);

#pragma unroll
  for (int r = 0; r < 4; r++) {
    int g = g0 + w * 16 + grp * 4 + r;
    int n = g >> 15;
    int s = (g >> 4) & 2047;
    int h = g & 15;
    u16* orow = Out + (((long)(n * NHEADS + h) * SEQ + s) << 6);
#pragma unroll
    for (int nt = 0; nt < 4; nt++)
      orow[nt * 16 + l15] = f2bf(acc[nt][r]);
  }
}

// ---------------------------------------------------------------------------
// V transpose: Vp [NH][S][64] -> Vt [NH][64][S]. 64x64 tiles.
__global__ __launch_bounds__(256) void transpose_v(
    const u16* __restrict__ Vp, u16* __restrict__ Vt)
{
  int st = blockIdx.x;
  int nh = blockIdx.y;
  __shared__ u16 Vs[64 * 65];
  int t = threadIdx.x;
  const u16* src = Vp + ((long)nh * SEQ + st * 64) * 64;
#pragma unroll
  for (int p = 0; p < 2; p++) {
    int row = p * 32 + (t >> 3);
    int c0 = (t & 7) * 8;
    u32x4 u = *(const u32x4*)(src + row * 64 + c0);
    u16x8 v = __builtin_bit_cast(u16x8, u);
#pragma unroll
    for (int j = 0; j < 8; j++) Vs[(c0 + j) * 65 + row] = v[j];
  }
  __syncthreads();
  int e = t >> 2, k0 = (t & 3) * 16;
  u16x8 lo, hi;
#pragma unroll
  for (int j = 0; j < 8; j++) { lo[j] = Vs[e * 65 + k0 + j]; hi[j] = Vs[e * 65 + k0 + 8 + j]; }
  u16* dst = Vt + ((long)nh * 64 + e) * SEQ + st * 64 + k0;
  *(u32x4*)dst = __builtin_bit_cast(u32x4, lo);
  *(u32x4*)(dst + 8) = __builtin_bit_cast(u32x4, hi);
}

// ---------------------------------------------------------------------------
__global__ __launch_bounds__(256) void conv_wo(
    const float* __restrict__ Wo, u16* __restrict__ Wob)
{
  int i = (blockIdx.x * 256 + threadIdx.x) * 4;
  f32x4 v = *(const f32x4*)(Wo + i);
  u32 w0 = cvtpk_bf16(v[0], v[1]);
  u32 w1 = cvtpk_bf16(v[2], v[3]);
  u64 pk = (u64)w0 | ((u64)w1 << 32);
  *(u64*)(Wob + i) = pk;
}

// ---------------------------------------------------------------------------
// Flash attention, 4 warps x 32 q-rows (128 q/block), KVBLK=64, 32x32x16 MFMA.
// Swapped QK^T (S^T = K·Q^T, lane owns one q-row), in-register softmax,
// double-buffered K/V LDS with ONE barrier per kv-tile, defer-max (THR=8 log2).
__global__ __launch_bounds__(256, 3) void attn_kernel(
    const u16* __restrict__ Qp, const u16* __restrict__ Kp, const u16* __restrict__ Vt,
    u16* __restrict__ AO)
{
  int nh = blockIdx.x;  // 0..63 (x=nh: q-blocks of a head share an XCD's L2)
  int qb = blockIdx.y;  // 0..15
  int n = nh >> 4, h = nh & 15;

  // [buf0: Ks 8K | Vs 8K][buf1: Ks 8K | Vs 8K]; epilogue Osm reuses [0:18432)
  __shared__ __align__(16) char smem[32768];

  int t = threadIdx.x, w = t >> 6, l = t & 63;
  int l31 = l & 31, hi = l >> 5;

  // Q as MFMA B-frag: lane holds Q[qrow=l31][d = dc*16 + hi*8 + j]
  long qrow = (long)nh * SEQ + qb * 128 + w * 32 + l31;
  const char* qbase = (const char*)Qp + qrow * 128;
  bf16x8 qf[4];
#pragma unroll
  for (int dc = 0; dc < 4; dc++)
    qf[dc] = __builtin_bit_cast(bf16x8, *(const u32x4*)(qbase + dc * 32 + hi * 16));

  f32x16 o0 = {}, o1 = {};  // O^T: C[e][q], e 0-31 / 32-63
  float mrun = -1e30f, lrun = 0.f;

  const char* Kg = (const char*)(Kp + (long)nh * SEQ * 64);
  const char* Vg = (const char*)(Vt + (long)nh * 64 * SEQ);

  // staging geometry: 512 chunks of 16B, thread t does chunks t and t+256
  int sr0 = t >> 3, sc = t & 7;
  int sr1 = sr0 + 32;
  int sphys0 = sr0 * 128 + ((sc ^ (sr0 & 7)) << 4);
  int sphys1 = sr1 * 128 + ((sc ^ (sr1 & 7)) << 4);

  u32x4 kreg[2], vreg[2];
  // tile 0: load + write into buf0
  kreg[0] = *(const u32x4*)(Kg + sr0 * 128 + sc * 16);
  kreg[1] = *(const u32x4*)(Kg + sr1 * 128 + sc * 16);
  vreg[0] = *(const u32x4*)(Vg + (long)sr0 * 4096 + sc * 16);
  vreg[1] = *(const u32x4*)(Vg + (long)sr1 * 4096 + sc * 16);
  *(u32x4*)(smem + sphys0) = kreg[0];
  *(u32x4*)(smem + sphys1) = kreg[1];
  *(u32x4*)(smem + 8192 + sphys0) = vreg[0];
  *(u32x4*)(smem + 8192 + sphys1) = vreg[1];
  // tile 1 prefetch into regs
  kreg[0] = *(const u32x4*)(Kg + 8192 + sr0 * 128 + sc * 16);
  kreg[1] = *(const u32x4*)(Kg + 8192 + sr1 * 128 + sc * 16);
  vreg[0] = *(const u32x4*)(Vg + (long)sr0 * 4096 + 128 + sc * 16);
  vreg[1] = *(const u32x4*)(Vg + (long)sr1 * 4096 + 128 + sc * 16);
  __syncthreads();

  for (int kt = 0; kt < 32; kt++) {
    const char* cur = smem + ((kt & 1) << 14);
    char* nxt = smem + (((kt + 1) & 1) << 14);
    const char* KsB = cur;
    const char* VsB = cur + 8192;

    // QK^T swapped: two C-tiles S^T[kv 0-31 / 32-63][q]
    f32x16 s0 = {}, s1 = {};
    __builtin_amdgcn_s_setprio(1);
#pragma unroll
    for (int dc = 0; dc < 4; dc++) {
      int cc = dc * 2 + hi;
      bf16x8 kf0 = __builtin_bit_cast(bf16x8,
          *(const u32x4*)(KsB + l31 * 128 + ((cc ^ (l31 & 7)) << 4)));
      s0 = mfma32(kf0, qf[dc], s0);
      int r1 = 32 + l31;
      bf16x8 kf1 = __builtin_bit_cast(bf16x8,
          *(const u32x4*)(KsB + r1 * 128 + ((cc ^ (r1 & 7)) << 4)));
      s1 = mfma32(kf1, qf[dc], s1);
    }
    __builtin_amdgcn_s_setprio(0);

    // stage tile kt+1 into the other buffer (hides under softmax VALU),
    // then issue global loads for tile kt+2
    if (kt + 1 < 32) {
      *(u32x4*)(nxt + sphys0) = kreg[0];
      *(u32x4*)(nxt + sphys1) = kreg[1];
      *(u32x4*)(nxt + 8192 + sphys0) = vreg[0];
      *(u32x4*)(nxt + 8192 + sphys1) = vreg[1];
      if (kt + 2 < 32) {
        const char* Kt = Kg + (long)(kt + 2) * 8192;
        kreg[0] = *(const u32x4*)(Kt + sr0 * 128 + sc * 16);
        kreg[1] = *(const u32x4*)(Kt + sr1 * 128 + sc * 16);
        vreg[0] = *(const u32x4*)(Vg + (long)sr0 * 4096 + (kt + 2) * 128 + sc * 16);
        vreg[1] = *(const u32x4*)(Vg + (long)sr1 * 4096 + (kt + 2) * 128 + sc * 16);
      }
    }

    // ---- in-register online softmax (exp2-space), defer-max THR=8 ----
    float m0 = fmaxf(s0[0], s1[0]), m1 = fmaxf(s0[1], s1[1]);
    float m2 = fmaxf(s0[2], s1[2]), m3 = fmaxf(s0[3], s1[3]);
#pragma unroll
    for (int r = 4; r < 16; r += 4) {
      m0 = fmaxf(m0, fmaxf(s0[r], s1[r]));
      m1 = fmaxf(m1, fmaxf(s0[r + 1], s1[r + 1]));
      m2 = fmaxf(m2, fmaxf(s0[r + 2], s1[r + 2]));
      m3 = fmaxf(m3, fmaxf(s0[r + 3], s1[r + 3]));
    }
    float mx = fmaxf(fmaxf(m0, m1), fmaxf(m2, m3));
    mx = fmaxf(mx, __shfl_xor(mx, 32));

    if (__any(mx > mrun + 8.0f)) {  // rescale only when P would exceed 2^8
      float mnew = fmaxf(mrun, mx);
      float scl = fexp2(mrun - mnew);
      mrun = mnew;
      lrun *= scl;
#pragma unroll
      for (int r = 0; r < 16; r++) { o0[r] *= scl; o1[r] *= scl; }
    }
#pragma unroll
    for (int r = 0; r < 16; r++) s0[r] = fexp2(s0[r] - mrun);
#pragma unroll
    for (int r = 0; r < 16; r++) s1[r] = fexp2(s1[r] - mrun);

    // tree-reduced row sum (depth ~6, no serial chain)
    {
      f32x16 sv = s0 + s1;
      f32x4 q4 = { sv[0] + sv[4], sv[1] + sv[5], sv[2] + sv[6], sv[3] + sv[7] };
      f32x4 q5 = { sv[8] + sv[12], sv[9] + sv[13], sv[10] + sv[14], sv[11] + sv[15] };
      f32x4 q6 = q4 + q5;
      lrun += (q6[0] + q6[1]) + (q6[2] + q6[3]);
    }

    // pack P^T into PV B-frags: 16 cvt_pk + 8 permlane32_swap
    bf16x8 pB[4];
    {
      u32 xw[8], wq[16];
#pragma unroll
      for (int i = 0; i < 8; i++) xw[i] = cvtpk_bf16(s0[2 * i], s0[2 * i + 1]);
      swap_words(xw[0], xw[2], hi, wq[0], wq[2]);
      swap_words(xw[1], xw[3], hi, wq[1], wq[3]);
      swap_words(xw[4], xw[6], hi, wq[4], wq[6]);
      swap_words(xw[5], xw[7], hi, wq[5], wq[7]);
#pragma unroll
      for (int i = 0; i < 8; i++) xw[i] = cvtpk_bf16(s1[2 * i], s1[2 * i + 1]);
      swap_words(xw[0], xw[2], hi, wq[8], wq[10]);
      swap_words(xw[1], xw[3], hi, wq[9], wq[11]);
      swap_words(xw[4], xw[6], hi, wq[12], wq[14]);
      swap_words(xw[5], xw[7], hi, wq[13], wq[15]);
#pragma unroll
      for (int kb = 0; kb < 4; kb++) {
        u32x4 v4 = { wq[kb * 4 + 0], wq[kb * 4 + 1], wq[kb * 4 + 2], wq[kb * 4 + 3] };
        pB[kb] = __builtin_bit_cast(bf16x8, v4);
      }
    }

    // PV: O^T += V^T · P^T
    __builtin_amdgcn_s_setprio(1);
#pragma unroll
    for (int kb = 0; kb < 4; kb++) {
      int cc = kb * 2 + hi;
      bf16x8 vf0 = __builtin_bit_cast(bf16x8,
          *(const u32x4*)(VsB + l31 * 128 + ((cc ^ (l31 & 7)) << 4)));
      o0 = mfma32(vf0, pB[kb], o0);
      int r1 = 32 + l31;
      bf16x8 vf1 = __builtin_bit_cast(bf16x8,
          *(const u32x4*)(VsB + r1 * 128 + ((cc ^ (r1 & 7)) << 4)));
      o1 = mfma32(vf1, pB[kb], o1);
    }
    __builtin_amdgcn_s_setprio(0);

    __syncthreads();  // single barrier per kv-tile
  }

  // epilogue: normalize, transpose via LDS, coalesced bf16 store to AO
  lrun += __shfl_xor(lrun, 32);
  float inv = 1.0f / lrun;
  int qlocal = w * 32 + l31;
  char* OsmB = smem;  // [128 q][72 u16] rows (144B, 16-aligned)
#pragma unroll
  for (int i = 0; i < 8; i++) {
    int e0 = ((2 * i) & 3) + 8 * ((2 * i) >> 2) + 4 * hi;
    u32 pk0 = cvtpk_bf16(o0[2 * i] * inv, o0[2 * i + 1] * inv);
    *(u32*)(OsmB + qlocal * 144 + 2 * e0) = pk0;
    u32 pk1 = cvtpk_bf16(o1[2 * i] * inv, o1[2 * i + 1] * inv);
    *(u32*)(OsmB + qlocal * 144 + 2 * (e0 + 32)) = pk1;
  }
  __syncthreads();
  int qr = t >> 1, half = t & 1;
  const char* src = OsmB + qr * 144 + half * 64;
  long qg = (long)qb * 128 + qr;
  char* dst = (char*)(AO + ((long)n * SEQ + qg) * EMB + h * 64 + half * 32);
#pragma unroll
  for (int j = 0; j < 4; j++)
    *(u32x4*)(dst + j * 16) = *(const u32x4*)(src + j * 16);
}

// ---------------------------------------------------------------------------
// Output GEMM: C[8192][1024] = AO[8192][1024] @ Wob[1024][1024]^T + bo, fp32 out.
// 128x128 tile, BK=32, dbuf LDS, ONE barrier per K-step.
__global__ __launch_bounds__(256) void gemm_out(
    const u16* __restrict__ A, const u16* __restrict__ B,
    const float* __restrict__ bias, float* __restrict__ C)
{
  int bm = blockIdx.x, bn = blockIdx.y;
  // [buf0: As 8K | Bs 8K][buf1: As 8K | Bs 8K]
  __shared__ __align__(16) char gsm[32768];
  int t = threadIdx.x, w = t >> 6, l = t & 63, l15 = l & 15, grp = l >> 4;
  int wm = w >> 1, wn = w & 1;
  f32x4 acc[4][4] = {};
  const char* Ab = (const char*)(A + (long)bm * 128 * 1024);
  const char* Bb = (const char*)(B + (long)bn * 128 * 1024);

  int srow = t >> 2, sc2 = t & 3;
  int srow1 = srow + 64;
  int sp0 = srow * 64 + ((sc2 ^ ((srow >> 1) & 3)) << 4);
  int sp1 = srow1 * 64 + ((sc2 ^ ((srow1 >> 1) & 3)) << 4);

  u32x4 areg[2], breg[2];
  // kt=0: load + write buf0
  areg[0] = *(const u32x4*)(Ab + (long)srow * 2048 + sc2 * 16);
  areg[1] = *(const u32x4*)(Ab + (long)srow1 * 2048 + sc2 * 16);
  breg[0] = *(const u32x4*)(Bb + (long)srow * 2048 + sc2 * 16);
  breg[1] = *(const u32x4*)(Bb + (long)srow1 * 2048 + sc2 * 16);
  *(u32x4*)(gsm + sp0) = areg[0];
  *(u32x4*)(gsm + sp1) = areg[1];
  *(u32x4*)(gsm + 8192 + sp0) = breg[0];
  *(u32x4*)(gsm + 8192 + sp1) = breg[1];
  // kt=1 prefetch
  areg[0] = *(const u32x4*)(Ab + (long)srow * 2048 + 64 + sc2 * 16);
  areg[1] = *(const u32x4*)(Ab + (long)srow1 * 2048 + 64 + sc2 * 16);
  breg[0] = *(const u32x4*)(Bb + (long)srow * 2048 + 64 + sc2 * 16);
  breg[1] = *(const u32x4*)(Bb + (long)srow1 * 2048 + 64 + sc2 * 16);
  __syncthreads();

  for (int kt = 0; kt < 32; kt++) {
    const char* AsB = gsm + ((kt & 1) << 14);
    const char* BsB = AsB + 8192;
    char* nxt = gsm + (((kt + 1) & 1) << 14);

    bf16x8 af[4], bf_[4];
#pragma unroll
    for (int i = 0; i < 4; i++) {
      int row = wm * 64 + i * 16 + l15;
      af[i] = __builtin_bit_cast(bf16x8,
          *(const u32x4*)(AsB + row * 64 + ((grp ^ ((row >> 1) & 3)) << 4)));
      int rowb = wn * 64 + i * 16 + l15;
      bf_[i] = __builtin_bit_cast(bf16x8,
          *(const u32x4*)(BsB + rowb * 64 + ((grp ^ ((rowb >> 1) & 3)) << 4)));
    }

    if (kt + 1 < 32) {
      *(u32x4*)(nxt + sp0) = areg[0];
      *(u32x4*)(nxt + sp1) = areg[1];
      *(u32x4*)(nxt + 8192 + sp0) = breg[0];
      *(u32x4*)(nxt + 8192 + sp1) = breg[1];
      if (kt + 2 < 32) {
        areg[0] = *(const u32x4*)(Ab + (long)srow * 2048 + (kt + 2) * 64 + sc2 * 16);
        areg[1] = *(const u32x4*)(Ab + (long)srow1 * 2048 + (kt + 2) * 64 + sc2 * 16);
        breg[0] = *(const u32x4*)(Bb + (long)srow * 2048 + (kt + 2) * 64 + sc2 * 16);
        breg[1] = *(const u32x4*)(Bb + (long)srow1 * 2048 + (kt + 2) * 64 + sc2 * 16);
      }
    }

    __builtin_amdgcn_s_setprio(1);
#pragma unroll
    for (int i = 0; i < 4; i++)
#pragma unroll
      for (int j = 0; j < 4; j++)
        acc[i][j] = mfma16(af[i], bf_[j], acc[i][j]);
    __builtin_amdgcn_s_setprio(0);

    __syncthreads();
  }

  float bv[4];
#pragma unroll
  for (int j = 0; j < 4; j++) bv[j] = bias[bn * 128 + wn * 64 + j * 16 + l15];
#pragma unroll
  for (int i = 0; i < 4; i++) {
#pragma unroll
    for (int r = 0; r < 4; r++) {
      long row = (long)bm * 128 + wm * 64 + i * 16 + grp * 4 + r;
      float* crow = C + row * 1024 + bn * 128 + wn * 64;
#pragma unroll
      for (int j = 0; j < 4; j++)
        crow[j * 16 + l15] = acc[i][j][r] + bv[j];
    }
  }
}

// ---------------------------------------------------------------------------
extern "C" void kernel_launch(void* const* d_in, const int* in_sizes, int n_in,
                              void* d_out, int out_size, void* d_ws, size_t ws_size,
                              hipStream_t stream)
{
  const float* Vx = (const float*)d_in[0];
  const float* Kx = (const float*)d_in[1];
  const float* Qx = (const float*)d_in[2];
  // d_in[3] = mask (unused by reference forward)
  const float* Wv = (const float*)d_in[4];
  const float* Wk = (const float*)d_in[5];
  const float* Wq = (const float*)d_in[6];
  const float* Wo = (const float*)d_in[7];
  const float* bo = (const float*)d_in[8];
  float* out = (float*)d_out;
  char* ws = (char*)d_ws;

  u16* Qp  = (u16*)(ws);
  u16* Kp  = (u16*)(ws + (1L << 24));
  u16* Vt  = (u16*)(ws + (2L << 24));
  u16* Vp  = (u16*)(ws + (3L << 24));  // reused as AO after transpose
  u16* AO  = Vp;
  u16* Wob = (u16*)(ws + (4L << 24));

  proj_kernel<<<dim3(2048, 3), 256, 0, stream>>>(Qx, Kx, Vx, Wq, Wk, Wv, Qp, Kp, Vp);
  transpose_v<<<dim3(32, 64), 256, 0, stream>>>(Vp, Vt);
  conv_wo<<<1024, 256, 0, stream>>>(Wo, Wob);
  attn_kernel<<<dim3(64, 16), 256, 0, stream>>>(Qp, Kp, Vt, AO);
  gemm_out<<<dim3(64, 8), 256, 0, stream>>>(AO, Wob, bo, out);
}